// Round 1
// baseline (779.922 us; speedup 1.0000x reference)
//
#include <hip/hip_runtime.h>
#include <cstddef>

typedef _Float16 h8 __attribute__((ext_vector_type(8)));
typedef _Float16 h4 __attribute__((ext_vector_type(4)));
typedef float f32x4 __attribute__((ext_vector_type(4)));

#define B_DIM 1024
#define T_DIM 1024
#define E_DIM 128
#define SW 136   // Wt LDS row stride (f16 elems), multiple of 8 for 16B-aligned b128 reads
#define SU 72    // U  LDS row stride (f16 elems)

// Padé [5/4] tanh: |err| < ~1e-4 for |x|<3 (|z| here ~N(0,0.57)); clamped to [-1,1].
__device__ __forceinline__ float tanh_fast(float x) {
  float x2 = x * x;
  float num = x * fmaf(x2, x2 + 105.0f, 945.0f);
  float den = fmaf(x2, fmaf(x2, 15.0f, 420.0f), 945.0f);
  float r = num * __builtin_amdgcn_rcpf(den);
  return fminf(fmaxf(r, -1.0f), 1.0f);
}

// Prologue: vT[e][t] = (f16) v[t][e]; bT[f][t] = (f32) b[t][f].  Both 128 x 1024.
// Turns the main kernel's per-tile column gathers of v/b into contiguous vector loads.
__global__ void prep_kernel(const float* __restrict__ vp, const float* __restrict__ bp,
                            _Float16* __restrict__ vT, float* __restrict__ bT) {
  __shared__ float tl[32][33];
  const float* src = blockIdx.z ? bp : vp;
  const int t0 = blockIdx.x * 32, e0 = blockIdx.y * 32;
  const int tx = threadIdx.x & 31, ty = threadIdx.x >> 5;
  #pragma unroll
  for (int r = ty; r < 32; r += 8)
    tl[r][tx] = src[(size_t)(t0 + r) * E_DIM + e0 + tx];
  __syncthreads();
  if (blockIdx.z == 0) {
    #pragma unroll
    for (int r = ty; r < 32; r += 8)
      vT[(size_t)(e0 + r) * T_DIM + t0 + tx] = (_Float16)tl[tx][r];
  } else {
    #pragma unroll
    for (int r = ty; r < 32; r += 8)
      bT[(size_t)(e0 + r) * T_DIM + t0 + tx] = tl[tx][r];
  }
}

// One block per batch b. 256 threads = 4 waves, 2 blocks/CU.
// Per T-tile (64 rows): step1 u = tanh(m_tile @ W_b + bias) via f16 MFMA (K=128),
// staged to double-buffered LDS in B-operand layout (1 barrier/tile); step2
// pre(128x128) += v_tile^T @ u (K=64). Next tile's m/v fragments are prefetched
// right after the barrier so HBM latency hides under step2 + next cvt.
// Epilogue: s[e]=colsum(m_b) (fp32 exact), softmax rows of pre, out = s^T alpha.
template <int USE_WS>
__global__ __launch_bounds__(256, 2)
void attn_mv_kernel(const float* __restrict__ mp, const float* __restrict__ vp,
                    const float* __restrict__ Wp, const float* __restrict__ bp,
                    const _Float16* __restrict__ vT, const float* __restrict__ bT,
                    float* __restrict__ outp)
{
  const int bi   = blockIdx.x;
  const int tid  = threadIdx.x;
  const int wv   = tid >> 6;     // wave 0..3
  const int lane = tid & 63;
  const int l15  = lane & 15;
  const int q    = lane >> 4;    // quad 0..3

  __shared__ _Float16 Wt[128 * SW];      // Wt[f][e]  (B-operand for step1) 34 KB
  __shared__ _Float16 U[2][128 * SU];    // U[m'][t]  double-buffered, 36.9 KB
  __shared__ float s_buf[4 * 128];
  __shared__ float s_fin[128];
  __shared__ float o_buf[4 * 128];

  // ---- stage W_b transposed as f16 (vectorized global read, scatter LDS write; once)
  const float* Wb = Wp + (size_t)bi * (E_DIM * E_DIM);
  for (int i = tid * 4; i < E_DIM * E_DIM; i += 1024) {
    const int e = i >> 7, f = i & 127;
    f32x4 w4 = *(const f32x4*)&Wb[i];
    Wt[(f    ) * SW + e] = (_Float16)w4[0];
    Wt[(f + 1) * SW + e] = (_Float16)w4[1];
    Wt[(f + 2) * SW + e] = (_Float16)w4[2];
    Wt[(f + 3) * SW + e] = (_Float16)w4[3];
  }

  // pre accumulators: wave wv owns e-rows [32*wv, 32*wv+32) -> 2 e-tiles x 8 n-tiles
  f32x4 pre[2][8];
  #pragma unroll
  for (int et = 0; et < 2; ++et)
    #pragma unroll
    for (int nt = 0; nt < 8; ++nt)
      #pragma unroll
      for (int r = 0; r < 4; ++r) pre[et][nt][r] = 0.0f;

  // per-lane column-sum partials: lane covers e = 32k + 8q + j
  float s_acc[4][8];
  #pragma unroll
  for (int k = 0; k < 4; ++k)
    #pragma unroll
    for (int j = 0; j < 8; ++j) s_acc[k][j] = 0.0f;

  const float* mblk = mp + (size_t)bi * T_DIM * E_DIM;

  // ---- preload tile 0 fragments (m rows + v A-fragments)
  f32x4 mnext[4][2];
  {
    const float* mrow = mblk + (size_t)(16 * wv + l15) * E_DIM;
    #pragma unroll
    for (int k = 0; k < 4; ++k) {
      const f32x4* p4 = (const f32x4*)(mrow + 32 * k + 8 * q);
      mnext[k][0] = p4[0];
      mnext[k][1] = p4[1];
    }
  }
  h8 vfn[2][2];
  if (USE_WS) {
    #pragma unroll
    for (int k2 = 0; k2 < 2; ++k2)
      #pragma unroll
      for (int et = 0; et < 2; ++et) {
        const int e = 32 * wv + 16 * et + l15;
        vfn[k2][et] = *(const h8*)&vT[(size_t)e * T_DIM + 32 * k2 + 8 * q];
      }
  } else {
    #pragma unroll
    for (int k2 = 0; k2 < 2; ++k2)
      #pragma unroll
      for (int et = 0; et < 2; ++et) {
        const int e = 32 * wv + 16 * et + l15;
        #pragma unroll
        for (int j = 0; j < 8; ++j) {
          const int t = 32 * k2 + 8 * q + j;
          vfn[k2][et][j] = (_Float16)vp[t * E_DIM + e];
        }
      }
  }

  __syncthreads();  // Wt ready

  int cur = 0;
  #pragma unroll 1
  for (int tile = 0; tile < 16; ++tile) {
    const int tb = tile * 64;

    // ---- convert prefetched m to f16 A-fragments, accumulate exact fp32 colsums
    h8 ma[4];
    #pragma unroll
    for (int k = 0; k < 4; ++k) {
      #pragma unroll
      for (int j = 0; j < 4; ++j) {
        s_acc[k][j]     += mnext[k][0][j];
        s_acc[k][4 + j] += mnext[k][1][j];
        ma[k][j]     = (_Float16)mnext[k][0][j];
        ma[k][4 + j] = (_Float16)mnext[k][1][j];
      }
    }
    // current-tile v fragments (prefetched last iteration)
    h8 va[2][2];
    #pragma unroll
    for (int k2 = 0; k2 < 2; ++k2) {
      va[k2][0] = vfn[k2][0];
      va[k2][1] = vfn[k2][1];
    }

    // ---- issue bias loads now; consumed after step1 (latency hides under MFMAs)
    f32x4 bfr[8];
    if (USE_WS) {
      #pragma unroll
      for (int ft = 0; ft < 8; ++ft) {
        const int f = 16 * ft + l15;
        bfr[ft] = *(const f32x4*)&bT[(size_t)f * T_DIM + tb + 16 * wv + 4 * q];
      }
    }

    // ---- step 1 MFMAs: u slab (16 t-rows x 128 f), K = 128 over e
    f32x4 uacc[8];
    #pragma unroll
    for (int ft = 0; ft < 8; ++ft)
      #pragma unroll
      for (int r = 0; r < 4; ++r) uacc[ft][r] = 0.0f;

    #pragma unroll
    for (int k = 0; k < 4; ++k) {
      #pragma unroll
      for (int ft = 0; ft < 8; ++ft) {
        h8 bw = *(const h8*)&Wt[(16 * ft + l15) * SW + 32 * k + 8 * q];
        uacc[ft] = __builtin_amdgcn_mfma_f32_16x16x32_f16(ma[k], bw, uacc[ft], 0, 0, 0);
      }
    }

    // ---- finalize u: + b[t,f] (b indexed by TIME per reference broadcast),
    //      tanh, cvt f16, store to U[cur][m'=f][t_local]
    #pragma unroll
    for (int ft = 0; ft < 8; ++ft) {
      const int f = 16 * ft + l15;
      h4 hv;
      if (USE_WS) {
        f32x4 z = uacc[ft] + bfr[ft];
        #pragma unroll
        for (int r = 0; r < 4; ++r) hv[r] = (_Float16)tanh_fast(z[r]);
      } else {
        #pragma unroll
        for (int r = 0; r < 4; ++r) {
          const int tg = tb + 16 * wv + 4 * q + r;   // C/D layout: row = 4q + r
          hv[r] = (_Float16)tanh_fast(uacc[ft][r] + bp[tg * E_DIM + f]);
        }
      }
      *(h4*)&U[cur][f * SU + 16 * wv + 4 * q] = hv;
    }

    __syncthreads();  // U[cur] complete (only barrier in the tile loop)

    // ---- prefetch next tile's m + v fragments (register loads; never cross a
    //      barrier before use, so no vmcnt drain — latency hides under step2)
    if (tile < 15) {
      const int tb2 = tb + 64;
      const float* mrow = mblk + (size_t)(tb2 + 16 * wv + l15) * E_DIM;
      #pragma unroll
      for (int k = 0; k < 4; ++k) {
        const f32x4* p4 = (const f32x4*)(mrow + 32 * k + 8 * q);
        mnext[k][0] = p4[0];
        mnext[k][1] = p4[1];
      }
      if (USE_WS) {
        #pragma unroll
        for (int k2 = 0; k2 < 2; ++k2)
          #pragma unroll
          for (int et = 0; et < 2; ++et) {
            const int e = 32 * wv + 16 * et + l15;
            vfn[k2][et] = *(const h8*)&vT[(size_t)e * T_DIM + tb2 + 32 * k2 + 8 * q];
          }
      } else {
        #pragma unroll
        for (int k2 = 0; k2 < 2; ++k2)
          #pragma unroll
          for (int et = 0; et < 2; ++et) {
            const int e = 32 * wv + 16 * et + l15;
            #pragma unroll
            for (int j = 0; j < 8; ++j) {
              const int t = tb2 + 32 * k2 + 8 * q + j;
              vfn[k2][et][j] = (_Float16)vp[t * E_DIM + e];
            }
          }
      }
    }

    // ---- step 2 MFMAs: pre += v^T @ u, K = 64 over t_local
    #pragma unroll
    for (int k2 = 0; k2 < 2; ++k2) {
      #pragma unroll
      for (int nt = 0; nt < 8; ++nt) {
        h8 bu = *(const h8*)&U[cur][(16 * nt + l15) * SU + 32 * k2 + 8 * q];
        pre[0][nt] = __builtin_amdgcn_mfma_f32_16x16x32_f16(va[k2][0], bu, pre[0][nt], 0, 0, 0);
        pre[1][nt] = __builtin_amdgcn_mfma_f32_16x16x32_f16(va[k2][1], bu, pre[1][nt], 0, 0, 0);
      }
    }
    cur ^= 1;
  }

  // ==== epilogue ====
  // s[e]: butterfly-sum the 16 lanes of each row group (they share the same e-set)
  #pragma unroll
  for (int k = 0; k < 4; ++k)
    #pragma unroll
    for (int j = 0; j < 8; ++j) {
      float t = s_acc[k][j];
      t += __shfl_xor(t, 1);
      t += __shfl_xor(t, 2);
      t += __shfl_xor(t, 4);
      t += __shfl_xor(t, 8);
      s_acc[k][j] = t;
    }
  if (l15 == 0) {
    #pragma unroll
    for (int k = 0; k < 4; ++k)
      #pragma unroll
      for (int j = 0; j < 8; ++j)
        s_buf[wv * 128 + 32 * k + 8 * q + j] = s_acc[k][j];
  }
  __syncthreads();
  if (tid < 128)
    s_fin[tid] = s_buf[tid] + s_buf[128 + tid] + s_buf[256 + tid] + s_buf[384 + tid];
  __syncthreads();

  // softmax over m' for each owned e-row; out partial = sum_e (s[e]/rowsum) * exp(pre)
  float o[8];
  #pragma unroll
  for (int nt = 0; nt < 8; ++nt) o[nt] = 0.0f;

  #pragma unroll
  for (int et = 0; et < 2; ++et) {
    #pragma unroll
    for (int r = 0; r < 4; ++r) {
      float mx = -3.0e38f;
      #pragma unroll
      for (int nt = 0; nt < 8; ++nt) mx = fmaxf(mx, pre[et][nt][r]);
      mx = fmaxf(mx, __shfl_xor(mx, 1));
      mx = fmaxf(mx, __shfl_xor(mx, 2));
      mx = fmaxf(mx, __shfl_xor(mx, 4));
      mx = fmaxf(mx, __shfl_xor(mx, 8));
      float p[8];
      float sum = 0.0f;
      #pragma unroll
      for (int nt = 0; nt < 8; ++nt) {
        p[nt] = __expf(pre[et][nt][r] - mx);
        sum += p[nt];
      }
      sum += __shfl_xor(sum, 1);
      sum += __shfl_xor(sum, 2);
      sum += __shfl_xor(sum, 4);
      sum += __shfl_xor(sum, 8);
      const int e = 32 * wv + 16 * et + 4 * q + r;
      const float wrow = s_fin[e] * __builtin_amdgcn_rcpf(sum);
      #pragma unroll
      for (int nt = 0; nt < 8; ++nt) o[nt] = fmaf(p[nt], wrow, o[nt]);
    }
  }
  // reduce the 4 quad-groups (rows 4q+r live in different quads)
  #pragma unroll
  for (int nt = 0; nt < 8; ++nt) {
    float t = o[nt];
    t += __shfl_xor(t, 16);
    t += __shfl_xor(t, 32);
    o[nt] = t;
  }
  if (q == 0) {
    #pragma unroll
    for (int nt = 0; nt < 8; ++nt)
      o_buf[wv * 128 + 16 * nt + l15] = o[nt];
  }
  __syncthreads();
  if (tid < 128)
    outp[(size_t)bi * E_DIM + tid] =
        o_buf[tid] + o_buf[128 + tid] + o_buf[256 + tid] + o_buf[384 + tid];
}

extern "C" void kernel_launch(void* const* d_in, const int* in_sizes, int n_in,
                              void* d_out, int out_size, void* d_ws, size_t ws_size,
                              hipStream_t stream) {
  const float* mp = (const float*)d_in[0];  // m (B,T,E) fp32
  const float* vp = (const float*)d_in[1];  // v (B,E)   fp32
  const float* Wp = (const float*)d_in[2];  // W (B,E,E) fp32
  const float* bp = (const float*)d_in[3];  // b (B,E)   fp32
  float* outp = (float*)d_out;              // out (B,E) fp32

  const size_t vT_bytes = (size_t)E_DIM * T_DIM * sizeof(_Float16);      // 256 KB
  const size_t need = vT_bytes + (size_t)E_DIM * T_DIM * sizeof(float);  // +512 KB

  if (d_ws != nullptr && ws_size >= need) {
    _Float16* vT = (_Float16*)d_ws;
    float* bT = (float*)((char*)d_ws + vT_bytes);
    prep_kernel<<<dim3(32, 4, 2), dim3(256), 0, stream>>>(vp, bp, vT, bT);
    attn_mv_kernel<1><<<dim3(B_DIM), dim3(256), 0, stream>>>(mp, vp, Wp, bp, vT, bT, outp);
  } else {
    attn_mv_kernel<0><<<dim3(B_DIM), dim3(256), 0, stream>>>(mp, vp, Wp, bp, nullptr, nullptr, outp);
  }
}

// Round 3
// 777.921 us; speedup vs baseline: 1.0026x; 1.0026x over previous
//
#include <hip/hip_runtime.h>
#include <cstddef>

typedef _Float16 h8 __attribute__((ext_vector_type(8)));
typedef _Float16 h4 __attribute__((ext_vector_type(4)));
typedef float f32x4 __attribute__((ext_vector_type(4)));

#define B_DIM 1024
#define T_DIM 1024
#define E_DIM 128
#define SW 136   // Wt LDS row stride (f16 elems), multiple of 8 for 16B-aligned b128 reads
#define SU 72    // U  LDS row stride (f16 elems)

// Padé [5/4] tanh: |err| < ~1e-4 for |x|<3 (|z| here ~N(0,0.57)); clamped to [-1,1].
__device__ __forceinline__ float tanh_fast(float x) {
  float x2 = x * x;
  float num = x * fmaf(x2, x2 + 105.0f, 945.0f);
  float den = fmaf(x2, fmaf(x2, 15.0f, 420.0f), 945.0f);
  float r = num * __builtin_amdgcn_rcpf(den);
  return fminf(fmaxf(r, -1.0f), 1.0f);
}

// Prologue: vT[e][t] = (f16) v[t][e]; bT[f][t] = (f16) b[t][f].  Both 128 x 1024 f16.
// Turns the main kernel's per-tile column gathers of v/b into contiguous vector loads.
__global__ void prep_kernel(const float* __restrict__ vp, const float* __restrict__ bp,
                            _Float16* __restrict__ vT, _Float16* __restrict__ bT) {
  __shared__ float tl[32][33];
  const float* src = blockIdx.z ? bp : vp;
  _Float16* dst = blockIdx.z ? bT : vT;
  const int t0 = blockIdx.x * 32, e0 = blockIdx.y * 32;
  const int tx = threadIdx.x & 31, ty = threadIdx.x >> 5;
  #pragma unroll
  for (int r = ty; r < 32; r += 8)
    tl[r][tx] = src[(size_t)(t0 + r) * E_DIM + e0 + tx];
  __syncthreads();
  #pragma unroll
  for (int r = ty; r < 32; r += 8)
    dst[(size_t)(e0 + r) * T_DIM + t0 + tx] = (_Float16)tl[tx][r];
}

// One block per batch b. 256 threads = 4 waves, 2 blocks/CU.
// Per T-tile (64 rows): step1 u = tanh(m_tile @ W_b + bias) via f16 MFMA (K=128),
// staged to double-buffered LDS in B-operand layout (1 barrier/tile); step2
// pre(128x128) += v_tile^T @ u (K=64). Next tile's m/v fragments are prefetched
// BEFORE the finalize+barrier so HBM latency hides under tanh+barrier+step2.
// Epilogue: s[e]=colsum(m_b) (fp32 exact), softmax rows of pre, out = s^T alpha.
// LDS bank audit: Wt reads (SW=136) and U reads (SU=72) both land bank-start
// 4*(l15+q) mod 32 -> 8 lanes per 4-bank group, all 32 banks busy 8 clks = b128
// floor; conflict-free in the throughput sense. No swizzle needed.
template <int USE_WS>
__global__ __launch_bounds__(256, 2)
void attn_mv_kernel(const float* __restrict__ mp, const float* __restrict__ vp,
                    const float* __restrict__ Wp, const float* __restrict__ bp,
                    const _Float16* __restrict__ vT, const _Float16* __restrict__ bT,
                    float* __restrict__ outp)
{
  const int bi   = blockIdx.x;
  const int tid  = threadIdx.x;
  const int wv   = tid >> 6;     // wave 0..3
  const int lane = tid & 63;
  const int l15  = lane & 15;
  const int q    = lane >> 4;    // quad 0..3

  __shared__ _Float16 Wt[128 * SW];      // Wt[f][e]  (B-operand for step1) 34 KB
  __shared__ _Float16 U[2][128 * SU];    // U[m'][t]  double-buffered, 36.9 KB
  __shared__ float s_buf[4 * 128];
  __shared__ float s_fin[128];
  __shared__ float o_buf[4 * 128];

  // ---- stage W_b transposed as f16 (vectorized global read, scatter LDS write; once)
  const float* Wb = Wp + (size_t)bi * (E_DIM * E_DIM);
  for (int i = tid * 4; i < E_DIM * E_DIM; i += 1024) {
    const int e = i >> 7, f = i & 127;
    f32x4 w4 = *(const f32x4*)&Wb[i];
    Wt[(f    ) * SW + e] = (_Float16)w4[0];
    Wt[(f + 1) * SW + e] = (_Float16)w4[1];
    Wt[(f + 2) * SW + e] = (_Float16)w4[2];
    Wt[(f + 3) * SW + e] = (_Float16)w4[3];
  }

  // pre accumulators: wave wv owns e-rows [32*wv, 32*wv+32) -> 2 e-tiles x 8 n-tiles
  f32x4 pre[2][8];
  #pragma unroll
  for (int et = 0; et < 2; ++et)
    #pragma unroll
    for (int nt = 0; nt < 8; ++nt)
      #pragma unroll
      for (int r = 0; r < 4; ++r) pre[et][nt][r] = 0.0f;

  // per-lane column-sum partials: lane covers e = 32k + 8q + j
  float s_acc[4][8];
  #pragma unroll
  for (int k = 0; k < 4; ++k)
    #pragma unroll
    for (int j = 0; j < 8; ++j) s_acc[k][j] = 0.0f;

  const float* mblk = mp + (size_t)bi * T_DIM * E_DIM;

  // ---- preload tile 0 fragments (m rows + v A-fragments)
  f32x4 mnext[4][2];
  {
    const float* mrow = mblk + (size_t)(16 * wv + l15) * E_DIM;
    #pragma unroll
    for (int k = 0; k < 4; ++k) {
      const f32x4* p4 = (const f32x4*)(mrow + 32 * k + 8 * q);
      mnext[k][0] = p4[0];
      mnext[k][1] = p4[1];
    }
  }
  h8 vfn[2][2];
  if (USE_WS) {
    #pragma unroll
    for (int k2 = 0; k2 < 2; ++k2)
      #pragma unroll
      for (int et = 0; et < 2; ++et) {
        const int e = 32 * wv + 16 * et + l15;
        vfn[k2][et] = *(const h8*)&vT[(size_t)e * T_DIM + 32 * k2 + 8 * q];
      }
  } else {
    #pragma unroll
    for (int k2 = 0; k2 < 2; ++k2)
      #pragma unroll
      for (int et = 0; et < 2; ++et) {
        const int e = 32 * wv + 16 * et + l15;
        #pragma unroll
        for (int j = 0; j < 8; ++j) {
          const int t = 32 * k2 + 8 * q + j;
          vfn[k2][et][j] = (_Float16)vp[t * E_DIM + e];
        }
      }
  }

  __syncthreads();  // Wt ready

  int cur = 0;
  #pragma unroll 1
  for (int tile = 0; tile < 16; ++tile) {
    const int tb = tile * 64;

    // ---- convert prefetched m to f16 A-fragments, accumulate exact fp32 colsums
    h8 ma[4];
    #pragma unroll
    for (int k = 0; k < 4; ++k) {
      #pragma unroll
      for (int j = 0; j < 4; ++j) {
        s_acc[k][j]     += mnext[k][0][j];
        s_acc[k][4 + j] += mnext[k][1][j];
        ma[k][j]     = (_Float16)mnext[k][0][j];
        ma[k][4 + j] = (_Float16)mnext[k][1][j];
      }
    }
    // current-tile v fragments (prefetched last iteration)
    h8 va[2][2];
    #pragma unroll
    for (int k2 = 0; k2 < 2; ++k2) {
      va[k2][0] = vfn[k2][0];
      va[k2][1] = vfn[k2][1];
    }

    // ---- issue bias loads now; consumed after step1 (latency hides under MFMAs)
    h4 bfr[8];
    if (USE_WS) {
      #pragma unroll
      for (int ft = 0; ft < 8; ++ft) {
        const int f = 16 * ft + l15;
        bfr[ft] = *(const h4*)&bT[(size_t)f * T_DIM + tb + 16 * wv + 4 * q];
      }
    }

    // ---- step 1 MFMAs: u slab (16 t-rows x 128 f), K = 128 over e
    f32x4 uacc[8];
    #pragma unroll
    for (int ft = 0; ft < 8; ++ft)
      #pragma unroll
      for (int r = 0; r < 4; ++r) uacc[ft][r] = 0.0f;

    __builtin_amdgcn_s_setprio(1);
    #pragma unroll
    for (int k = 0; k < 4; ++k) {
      #pragma unroll
      for (int ft = 0; ft < 8; ++ft) {
        h8 bw = *(const h8*)&Wt[(16 * ft + l15) * SW + 32 * k + 8 * q];
        uacc[ft] = __builtin_amdgcn_mfma_f32_16x16x32_f16(ma[k], bw, uacc[ft], 0, 0, 0);
      }
    }
    __builtin_amdgcn_s_setprio(0);

    // ---- prefetch next tile's m + v fragments NOW (before finalize+barrier):
    //      reg-destined loads; latency hides under tanh + barrier + step2 (~1500 cyc)
    if (tile < 15) {
      const int tb2 = tb + 64;
      const float* mrow = mblk + (size_t)(tb2 + 16 * wv + l15) * E_DIM;
      #pragma unroll
      for (int k = 0; k < 4; ++k) {
        const f32x4* p4 = (const f32x4*)(mrow + 32 * k + 8 * q);
        mnext[k][0] = p4[0];
        mnext[k][1] = p4[1];
      }
      if (USE_WS) {
        #pragma unroll
        for (int k2 = 0; k2 < 2; ++k2)
          #pragma unroll
          for (int et = 0; et < 2; ++et) {
            const int e = 32 * wv + 16 * et + l15;
            vfn[k2][et] = *(const h8*)&vT[(size_t)e * T_DIM + tb2 + 32 * k2 + 8 * q];
          }
      } else {
        #pragma unroll
        for (int k2 = 0; k2 < 2; ++k2)
          #pragma unroll
          for (int et = 0; et < 2; ++et) {
            const int e = 32 * wv + 16 * et + l15;
            #pragma unroll
            for (int j = 0; j < 8; ++j) {
              const int t = tb2 + 32 * k2 + 8 * q + j;
              vfn[k2][et][j] = (_Float16)vp[t * E_DIM + e];
            }
          }
      }
    }

    // ---- finalize u: + b[t,f] (b indexed by TIME per reference broadcast),
    //      tanh, cvt f16, store to U[cur][m'=f][t_local]
    #pragma unroll
    for (int ft = 0; ft < 8; ++ft) {
      const int f = 16 * ft + l15;
      h4 hv;
      if (USE_WS) {
        #pragma unroll
        for (int r = 0; r < 4; ++r) {
          float z = uacc[ft][r] + (float)bfr[ft][r];
          hv[r] = (_Float16)tanh_fast(z);
        }
      } else {
        #pragma unroll
        for (int r = 0; r < 4; ++r) {
          const int tg = tb + 16 * wv + 4 * q + r;   // C/D layout: row = 4q + r
          hv[r] = (_Float16)tanh_fast(uacc[ft][r] + bp[tg * E_DIM + f]);
        }
      }
      *(h4*)&U[cur][f * SU + 16 * wv + 4 * q] = hv;
    }

    __syncthreads();  // U[cur] complete (only barrier in the tile loop)

    // ---- step 2 MFMAs: pre += v^T @ u, K = 64 over t_local
    __builtin_amdgcn_s_setprio(1);
    #pragma unroll
    for (int k2 = 0; k2 < 2; ++k2) {
      #pragma unroll
      for (int nt = 0; nt < 8; ++nt) {
        h8 bu = *(const h8*)&U[cur][(16 * nt + l15) * SU + 32 * k2 + 8 * q];
        pre[0][nt] = __builtin_amdgcn_mfma_f32_16x16x32_f16(va[k2][0], bu, pre[0][nt], 0, 0, 0);
        pre[1][nt] = __builtin_amdgcn_mfma_f32_16x16x32_f16(va[k2][1], bu, pre[1][nt], 0, 0, 0);
      }
    }
    __builtin_amdgcn_s_setprio(0);
    cur ^= 1;
  }

  // ==== epilogue ====
  // s[e]: butterfly-sum the 16 lanes of each row group (they share the same e-set)
  #pragma unroll
  for (int k = 0; k < 4; ++k)
    #pragma unroll
    for (int j = 0; j < 8; ++j) {
      float t = s_acc[k][j];
      t += __shfl_xor(t, 1);
      t += __shfl_xor(t, 2);
      t += __shfl_xor(t, 4);
      t += __shfl_xor(t, 8);
      s_acc[k][j] = t;
    }
  if (l15 == 0) {
    #pragma unroll
    for (int k = 0; k < 4; ++k)
      #pragma unroll
      for (int j = 0; j < 8; ++j)
        s_buf[wv * 128 + 32 * k + 8 * q + j] = s_acc[k][j];
  }
  __syncthreads();
  if (tid < 128)
    s_fin[tid] = s_buf[tid] + s_buf[128 + tid] + s_buf[256 + tid] + s_buf[384 + tid];
  __syncthreads();

  // softmax over m' for each owned e-row; out partial = sum_e (s[e]/rowsum) * exp(pre)
  float o[8];
  #pragma unroll
  for (int nt = 0; nt < 8; ++nt) o[nt] = 0.0f;

  #pragma unroll
  for (int et = 0; et < 2; ++et) {
    #pragma unroll
    for (int r = 0; r < 4; ++r) {
      float mx = -3.0e38f;
      #pragma unroll
      for (int nt = 0; nt < 8; ++nt) mx = fmaxf(mx, pre[et][nt][r]);
      mx = fmaxf(mx, __shfl_xor(mx, 1));
      mx = fmaxf(mx, __shfl_xor(mx, 2));
      mx = fmaxf(mx, __shfl_xor(mx, 4));
      mx = fmaxf(mx, __shfl_xor(mx, 8));
      float p[8];
      float sum = 0.0f;
      #pragma unroll
      for (int nt = 0; nt < 8; ++nt) {
        p[nt] = __expf(pre[et][nt][r] - mx);
        sum += p[nt];
      }
      sum += __shfl_xor(sum, 1);
      sum += __shfl_xor(sum, 2);
      sum += __shfl_xor(sum, 4);
      sum += __shfl_xor(sum, 8);
      const int e = 32 * wv + 16 * et + 4 * q + r;
      const float wrow = s_fin[e] * __builtin_amdgcn_rcpf(sum);
      #pragma unroll
      for (int nt = 0; nt < 8; ++nt) o[nt] = fmaf(p[nt], wrow, o[nt]);
    }
  }
  // reduce the 4 quad-groups (rows 4q+r live in different quads)
  #pragma unroll
  for (int nt = 0; nt < 8; ++nt) {
    float t = o[nt];
    t += __shfl_xor(t, 16);
    t += __shfl_xor(t, 32);
    o[nt] = t;
  }
  if (q == 0) {
    #pragma unroll
    for (int nt = 0; nt < 8; ++nt)
      o_buf[wv * 128 + 16 * nt + l15] = o[nt];
  }
  __syncthreads();
  if (tid < 128)
    outp[(size_t)bi * E_DIM + tid] =
        o_buf[tid] + o_buf[128 + tid] + o_buf[256 + tid] + o_buf[384 + tid];
}

extern "C" void kernel_launch(void* const* d_in, const int* in_sizes, int n_in,
                              void* d_out, int out_size, void* d_ws, size_t ws_size,
                              hipStream_t stream) {
  const float* mp = (const float*)d_in[0];  // m (B,T,E) fp32
  const float* vp = (const float*)d_in[1];  // v (B,E)   fp32
  const float* Wp = (const float*)d_in[2];  // W (B,E,E) fp32
  const float* bp = (const float*)d_in[3];  // b (B,E)   fp32
  float* outp = (float*)d_out;              // out (B,E) fp32

  const size_t vT_bytes = (size_t)E_DIM * T_DIM * sizeof(_Float16);  // 256 KB
  const size_t need = 2 * vT_bytes;                                  // vT + bT (f16)

  if (d_ws != nullptr && ws_size >= need) {
    _Float16* vT = (_Float16*)d_ws;
    _Float16* bT = (_Float16*)((char*)d_ws + vT_bytes);
    prep_kernel<<<dim3(32, 4, 2), dim3(256), 0, stream>>>(vp, bp, vT, bT);
    attn_mv_kernel<1><<<dim3(B_DIM), dim3(256), 0, stream>>>(mp, vp, Wp, bp, vT, bT, outp);
  } else {
    attn_mv_kernel<0><<<dim3(B_DIM), dim3(256), 0, stream>>>(mp, vp, Wp, bp, nullptr, nullptr, outp);
  }
}